// Round 12
// baseline (699.681 us; speedup 1.0000x reference)
//
#include <hip/hip_runtime.h>
#include <hip/hip_bf16.h>

#define TT 128
#define BATCH 64
#define WCH 16
#define CEMB 32
#define CCH 128
#define HID 512
#define GATES 2048
#define INF_ 428
#define KP 448
#define NOUT 20

typedef float f32x4 __attribute__((ext_vector_type(4)));
typedef __bf16 b8v __attribute__((ext_vector_type(8)));
typedef unsigned int u32x2 __attribute__((ext_vector_type(2)));
typedef unsigned int u32x4 __attribute__((ext_vector_type(4)));
typedef __hip_bfloat16 bf16;

__device__ __forceinline__ float sigm(float x){ return 1.f/(1.f+__expf(-x)); }
__device__ __forceinline__ float tanh_(float x){ float e=__expf(2.f*x); return (e-1.f)/(e+1.f); }

// ---------------- merged prep: feat build (blocks 0..4095, 2 words/block) +
// weight pack (blocks 4096..6143).
__global__ __launch_bounds__(256) void k_prep(
    const int* __restrict__ words, const int* __restrict__ chars,
    const float* __restrict__ embW, const float* __restrict__ cembW,
    const float* __restrict__ convW, const float* __restrict__ convb,
    const float* __restrict__ WihF, const float* __restrict__ WhhF,
    const float* __restrict__ bihF, const float* __restrict__ bhhF,
    const float* __restrict__ WihB, const float* __restrict__ WhhB,
    const float* __restrict__ bihB, const float* __restrict__ bhhB,
    bf16* __restrict__ featb, bf16* __restrict__ Wihp,
    bf16* __restrict__ Whhp, float* __restrict__ bsum) {
  const int tid = threadIdx.x;
  if (blockIdx.x < 4096) {
    int r = blockIdx.x*2 + (tid >> 7);
    int t2 = tid & 127;
    int t = r >> 6, b = r & 63;
    int wi = words[t*BATCH + b];
    const float* src = embW + (size_t)wi * 300;
    bf16* dst = featb + (size_t)r * KP;
    for (int k = t2; k < 300; k += 128) dst[k] = __float2bfloat16(src[k]);
    if (t2 < KP - INF_) dst[INF_ + t2] = __float2bfloat16(0.f);
    int cc = t2, g = cc >> 2;
    const int* ch = chars + ((size_t)b*TT + t)*WCH;
    float ce[WCH];
    #pragma unroll
    for (int w = 0; w < WCH; ++w) ce[w] = cembW[ch[w]*CEMB + g];
    float w0 = convW[cc*3], w1 = convW[cc*3+1], w2 = convW[cc*3+2];
    float m = -1e30f;
    #pragma unroll
    for (int p = 0; p < WCH-2; ++p) m = fmaxf(m, ce[p]*w0 + ce[p+1]*w1 + ce[p+2]*w2);
    dst[300 + cc] = __float2bfloat16(m + convb[cc]);
  } else {
    size_t tid0 = (size_t)(blockIdx.x - 4096)*256 + tid;
    size_t nthr = (size_t)2048*256;
    for (size_t idx = tid0; idx < (size_t)2*GATES*HID; idx += nthr) {
      int k = idx & (HID-1);
      int p = (idx >> 9) & (GATES-1);
      int d = (int)(idx >> 20);
      int j = ((p>>5)<<3) | (p&7);
      int tau = (p>>3)&3;
      const float* Whh = d ? WhhB : WhhF;
      Whhp[idx] = __float2bfloat16(Whh[(size_t)(tau*HID + j)*HID + k]);
    }
    for (size_t idx = tid0; idx < (size_t)2*GATES*KP; idx += nthr) {
      int k = (int)(idx % KP);
      size_t rest = idx / KP;
      int p = (int)(rest & (GATES-1));
      int d = (int)(rest >> 11);
      int j = ((p>>5)<<3) | (p&7);
      int tau = (p>>3)&3;
      const float* Wih = d ? WihB : WihF;
      float v = (k < INF_) ? Wih[(size_t)(tau*HID + j)*INF_ + k] : 0.f;
      Wihp[idx] = __float2bfloat16(v);
    }
    for (size_t idx = tid0; idx < (size_t)2*GATES; idx += nthr) {
      int p = (int)(idx & (GATES-1));
      int d = (int)(idx >> 11);
      int j = ((p>>5)<<3) | (p&7);
      int tau = (p>>3)&3;
      int gg = tau*HID + j;
      bsum[idx] = d ? (bihB[gg]+bhhB[gg]) : (bihF[gg]+bhhF[gg]);
    }
  }
}

// ---------------- fused producer/consumer.
// blocks 128..255: xW GEMM, outward-in t-pair order, sc0/sc1 stores, tflags counter.
// blocks 0..127:   persistent recurrence (r11 protocol) gated on tflags.
__global__ __launch_bounds__(256, 1) void k_fused(
    const bf16* __restrict__ Whhp, const bf16* __restrict__ Wihp,
    const bf16* __restrict__ featb, const float* __restrict__ bsum,
    bf16* __restrict__ xW, bf16* __restrict__ hs,
    unsigned* __restrict__ flags, unsigned* __restrict__ tflags) {
  __shared__ __align__(16) char smem[36864];
  const int tid = threadIdx.x;

  if (blockIdx.x >= 128) {
    // ================= GEMM producer =================
    typedef short sh72[72];
    sh72* As = (sh72*)smem;                      // 128 x 72 shorts = 18432 B
    sh72* Bs = (sh72*)(smem + 18432);
    const int g = blockIdx.x - 128;
    const int lane = tid & 63;
    const int wid4 = tid >> 6;
    const int wr = wid4 >> 1, wc = wid4 & 1;
    const int lm = lane & 15, kg = lane >> 4;
    for (int q = g; q < 2048; q += 128) {
      const int n_ord = q >> 5, m = q & 31;
      const int nblk = (n_ord & 1) ? (63 - (n_ord >> 1)) : (n_ord >> 1);
      const int m0 = m << 7, n0 = nblk << 7;
      f32x4 acc[4][4] = {};
      for (int k0 = 0; k0 < KP; k0 += 64) {
        #pragma unroll
        for (int c = 0; c < 4; ++c) {
          int ch = tid + c*256;
          int row = ch >> 3, k8 = (ch & 7) << 3;
          *(b8v*)&As[row][k8] = *(const b8v*)&Wihp[(size_t)(m0+row)*KP + k0 + k8];
          *(b8v*)&Bs[row][k8] = *(const b8v*)&featb[(size_t)(n0+row)*KP + k0 + k8];
        }
        __syncthreads();
        #pragma unroll
        for (int ks = 0; ks < 2; ++ks) {
          b8v a[4], bb[4];
          #pragma unroll
          for (int i = 0; i < 4; ++i) a[i]  = *(const b8v*)&As[wr*64 + i*16 + lm][ks*32 + kg*8];
          #pragma unroll
          for (int i = 0; i < 4; ++i) bb[i] = *(const b8v*)&Bs[wc*64 + i*16 + lm][ks*32 + kg*8];
          #pragma unroll
          for (int mi = 0; mi < 4; ++mi)
            #pragma unroll
            for (int ni = 0; ni < 4; ++ni)
              acc[mi][ni] = __builtin_amdgcn_mfma_f32_16x16x32_bf16(a[mi], bb[ni], acc[mi][ni], 0, 0, 0);
        }
        __syncthreads();
      }
      // epilogue: 4 consecutive noff -> one packed dwordx2 sc store
      #pragma unroll
      for (int mi = 0; mi < 4; ++mi) {
        #pragma unroll
        for (int ni = 0; ni < 4; ++ni) {
          int r = n0 + wc*64 + ni*16 + lm;
          int t = r >> 6, b = r & 63;
          int G = m0 + wr*64 + mi*16 + kg*4;       // reg 0 gate index
          int d = G >> 11, p = G & (GATES-1);
          int jt_ = p >> 5, pp = p & 31;
          int noff = ((pp>>2)&3)*8 + (pp>>4)*4;    // + reg (0..3) contiguous
          unsigned us[4];
          #pragma unroll
          for (int reg = 0; reg < 4; ++reg) {
            float v = acc[mi][ni][reg] + bsum[G + reg];
            us[reg] = (unsigned)__builtin_bit_cast(unsigned short, __float2bfloat16(v));
          }
          u32x2 pk; pk.x = us[0] | (us[1] << 16); pk.y = us[2] | (us[3] << 16);
          bf16* dst = xW + (((size_t)t*2 + d)*64 + jt_)*2048 + b*32 + noff;
          asm volatile("global_store_dwordx2 %0, %1, off sc0 sc1"
                       :: "v"(dst), "v"(pk) : "memory");
        }
      }
      asm volatile("s_waitcnt vmcnt(0)" ::: "memory");
      __syncthreads();
      if (tid == 0) atomicAdd(&tflags[nblk], 1u);   // device-scope; 32 => pair ready
    }
    return;
  }

  // ================= persist consumer =================
  bf16* hlds = (bf16*)smem;   // [b:16][slot:64][8], slot = j8 ^ (b&7)
  const int widx = tid >> 6;
  const int wid = blockIdx.x*4 + widx;
  const int lane = tid & 63;
  const int dir = wid >> 8;
  const int btile = (wid >> 6) & 3;
  const int jt = wid & 63;
  const int grp = blockIdx.x >> 4;                       // dir*4 + btile
  const int wv = ((blockIdx.x & 15) << 2) | widx;        // wave slot in group
  const int b0 = btile << 4, pbase = jt << 5, jbase = jt << 3;
  const int col = lane & 15, kg = lane >> 4;

  u32x4 wq0[16], wq1[16];
  {
    const bf16* wp = Whhp + (size_t)dir*GATES*HID;
    #pragma unroll
    for (int ks = 0; ks < 16; ++ks) {
      wq0[ks] = *(const u32x4*)&wp[(size_t)(pbase + col)*HID + ks*32 + kg*8];
      wq1[ks] = *(const u32x4*)&wp[(size_t)(pbase + 16 + col)*HID + ks*32 + kg*8];
    }
    #pragma unroll
    for (int ks = 0; ks < 16; ++ks) {
      asm volatile("" : "+v"(wq0[ks]));
      asm volatile("" : "+v"(wq1[ks]));
    }
  }
  const bf16* const xwbase = xW + (size_t)jt*2048 + (b0 + col)*32 + kg*8;
  u32x4 nxu;
  {
    const int t0 = dir ? TT-1 : 0;
    const unsigned* tf0 = tflags + (t0 >> 1);
    unsigned tv;
    do {
      asm volatile("global_load_dword %0, %1, off sc0 sc1\n\ts_waitcnt vmcnt(0)"
                   : "=v"(tv) : "v"(tf0) : "memory");
    } while (tv < 32u);
    const bf16* xaddr = xwbase + (size_t)(t0*2 + dir)*64*2048;
    asm volatile("global_load_dwordx4 %0, %1, off sc0 sc1\n\ts_waitcnt vmcnt(0)"
                 : "=v"(nxu) : "v"(xaddr) : "memory");
    __builtin_amdgcn_sched_barrier(0);
  }
  f32x4 creg = {0.f, 0.f, 0.f, 0.f};

  for (int step = 0; step < TT; ++step) {
    const int tcur = dir ? (TT-1-step) : step;
    f32x4 acc0, acc1;
    if (step > 0) {
      // ---- wave 0 polls all 64 producer flags of this group (prev step) ----
      if (widx == 0) {
        const unsigned* fp = flags + (((size_t)(step-1)*8 + grp) << 6) + lane;
        for (;;) {
          unsigned v;
          asm volatile("global_load_dword %0, %1, off sc0 sc1\n\ts_waitcnt vmcnt(0)"
                       : "=v"(v) : "v"(fp) : "memory");
          if (__all(v == (unsigned)step)) break;
        }
      }
      __syncthreads();
      // ---- stage h(prev) for this btile: 16KB, once per block, swizzled ----
      const int tprev = dir ? tcur+1 : tcur-1;
      const bf16* hbase = hs + (((size_t)dir*TT + tprev)*BATCH + b0)*HID;
      u32x4 tmp0, tmp1, tmp2, tmp3;
      {
        const bf16* a0 = hbase + (size_t)tid*8;
        const bf16* a1 = a0 + 2048;
        const bf16* a2 = a0 + 4096;
        const bf16* a3 = a0 + 6144;
        asm volatile("global_load_dwordx4 %0, %1, off sc0 sc1" : "=v"(tmp0) : "v"(a0) : "memory");
        asm volatile("global_load_dwordx4 %0, %1, off sc0 sc1" : "=v"(tmp1) : "v"(a1) : "memory");
        asm volatile("global_load_dwordx4 %0, %1, off sc0 sc1" : "=v"(tmp2) : "v"(a2) : "memory");
        asm volatile("global_load_dwordx4 %0, %1, off sc0 sc1" : "=v"(tmp3) : "v"(a3) : "memory");
      }
      asm volatile("s_waitcnt vmcnt(0)" ::: "memory");   // h loads + nxu ready
      __builtin_amdgcn_sched_barrier(0);
      #pragma unroll
      for (int p = 0; p < 4; ++p) {
        int c = p*256 + tid;
        int b = c >> 6, j8 = c & 63;
        int slot = j8 ^ (b & 7);
        u32x4 val = (p==0) ? tmp0 : (p==1) ? tmp1 : (p==2) ? tmp2 : tmp3;
        *(u32x4*)&hlds[b*512 + slot*8] = val;
      }
      __syncthreads();
      b8v nx = __builtin_bit_cast(b8v, nxu);
      #pragma unroll
      for (int r = 0; r < 4; ++r) { acc0[r] = (float)nx[r]; acc1[r] = (float)nx[r+4]; }
      #pragma unroll
      for (int ks = 0; ks < 16; ++ks) {
        int slotr = (ks*4 + kg) ^ (col & 7);
        b8v bfrag = *(const b8v*)&hlds[col*512 + slotr*8];
        acc0 = __builtin_amdgcn_mfma_f32_16x16x32_bf16(__builtin_bit_cast(b8v, wq0[ks]), bfrag, acc0, 0, 0, 0);
        acc1 = __builtin_amdgcn_mfma_f32_16x16x32_bf16(__builtin_bit_cast(b8v, wq1[ks]), bfrag, acc1, 0, 0, 0);
      }
    } else {
      b8v nx = __builtin_bit_cast(b8v, nxu);
      #pragma unroll
      for (int r = 0; r < 4; ++r) { acc0[r] = (float)nx[r]; acc1[r] = (float)nx[r+4]; }
    }
    f32x4 fsh, osh;
    #pragma unroll
    for (int r = 0; r < 4; ++r) {
      fsh[r] = __shfl_xor(acc0[r], 32);
      osh[r] = __shfl_xor(acc1[r], 32);
    }
    if (lane < 32) {
      unsigned us[4];
      #pragma unroll
      for (int r = 0; r < 4; ++r) {
        float zi = acc0[r], zf = fsh[r], zg = acc1[r], zo = osh[r];
        float co = (step > 0) ? creg[r] : 0.f;
        float cn = sigm(zf)*co + sigm(zi)*tanh_(zg);
        creg[r] = cn;
        us[r] = (unsigned)__builtin_bit_cast(unsigned short, __float2bfloat16(sigm(zo)*tanh_(cn)));
      }
      u32x2 pk; pk.x = us[0] | (us[1] << 16); pk.y = us[2] | (us[3] << 16);
      bf16* hpw = hs + (((size_t)dir*TT + tcur)*BATCH + b0 + col)*HID + jbase + kg*4;
      asm volatile("global_store_dwordx2 %0, %1, off sc0 sc1"
                   :: "v"(hpw), "v"(pk) : "memory");
    }
    if (step + 1 < TT) {
      const int tnext = dir ? tcur-1 : tcur+1;
      const unsigned* tf = tflags + (tnext >> 1);
      unsigned tv;
      // fire gate load first; its latency overlaps the h-store drain
      asm volatile("global_load_dword %0, %1, off sc0 sc1" : "=v"(tv) : "v"(tf) : "memory");
      asm volatile("s_waitcnt vmcnt(0)" ::: "memory");   // drains h stores + tv
      if (lane == 0) {
        unsigned* fw = flags + (((size_t)step*8 + grp) << 6) + wv;
        unsigned val = (unsigned)(step + 1);
        asm volatile("global_store_dword %0, %1, off sc0 sc1"
                     :: "v"(fw), "v"(val) : "memory");
      }
      while (tv < 32u) {   // xW pair for tnext not yet produced (early steps only)
        asm volatile("global_load_dword %0, %1, off sc0 sc1\n\ts_waitcnt vmcnt(0)"
                     : "=v"(tv) : "v"(tf) : "memory");
      }
      const bf16* xaddr = xwbase + (size_t)(tnext*2 + dir)*64*2048;
      asm volatile("global_load_dwordx4 %0, %1, off sc0 sc1"
                   : "=v"(nxu) : "v"(xaddr) : "memory");
    }
  }
}

// ---------------- final FC (separate launch: kernel boundary = full coherence)
__global__ __launch_bounds__(256) void k_fc(const bf16* __restrict__ hs,
                     const float* __restrict__ fcW,
                     const float* __restrict__ fcb, float* __restrict__ out) {
  int t = blockIdx.x;
  for (int item = threadIdx.x; item < BATCH*NOUT; item += 256) {
    const int b = item / NOUT, o = item - b*NOUT;
    const b8v* hf8 = (const b8v*)(hs + ((size_t)t*BATCH + b)*HID);
    const b8v* hb8 = (const b8v*)(hs + (((size_t)TT + t)*BATCH + b)*HID);
    const float4* w4 = (const float4*)(fcW + (size_t)o*2*HID);
    float s = fcb[o];
    #pragma unroll 4
    for (int k = 0; k < 64; ++k) {
      b8v hv = hf8[k];
      float4 wa = w4[2*k], wb = w4[2*k+1];
      s += (float)hv[0]*wa.x + (float)hv[1]*wa.y + (float)hv[2]*wa.z + (float)hv[3]*wa.w
         + (float)hv[4]*wb.x + (float)hv[5]*wb.y + (float)hv[6]*wb.z + (float)hv[7]*wb.w;
    }
    #pragma unroll 4
    for (int k = 0; k < 64; ++k) {
      b8v hv = hb8[k];
      float4 wa = w4[128 + 2*k], wb = w4[129 + 2*k];
      s += (float)hv[0]*wa.x + (float)hv[1]*wa.y + (float)hv[2]*wa.z + (float)hv[3]*wa.w
         + (float)hv[4]*wb.x + (float)hv[5]*wb.y + (float)hv[6]*wb.z + (float)hv[7]*wb.w;
    }
    out[((size_t)t*BATCH + b)*NOUT + o] = s;
  }
}

extern "C" void kernel_launch(void* const* d_in, const int* in_sizes, int n_in,
                              void* d_out, int out_size, void* d_ws, size_t ws_size,
                              hipStream_t stream) {
  const int* words = (const int*)d_in[0];
  const int* chars = (const int*)d_in[1];
  const float* embW = (const float*)d_in[2];
  const float* cembW = (const float*)d_in[3];
  const float* convW = (const float*)d_in[4];
  const float* convb = (const float*)d_in[5];
  const float* WihF = (const float*)d_in[6];
  const float* WhhF = (const float*)d_in[7];
  const float* bihF = (const float*)d_in[8];
  const float* bhhF = (const float*)d_in[9];
  const float* WihB = (const float*)d_in[10];
  const float* WhhB = (const float*)d_in[11];
  const float* bihB = (const float*)d_in[12];
  const float* bhhB = (const float*)d_in[13];
  const float* fcW = (const float*)d_in[14];
  const float* fcb = (const float*)d_in[15];
  float* out = (float*)d_out;

  char* ws = (char*)d_ws;
  size_t off = 0;
  bf16* xW    = (bf16*)(ws + off); off += (size_t)TT*2*GATES*BATCH*2;  // 64 MiB
  bf16* hsbuf = (bf16*)(ws + off); off += (size_t)2*TT*BATCH*HID*2;    // 16 MiB
  bf16* featb = (bf16*)(ws + off); off += (size_t)TT*BATCH*KP*2;       // 7 MiB
  bf16* Wihp  = (bf16*)(ws + off); off += (size_t)2*GATES*KP*2;        // 3.5 MiB
  bf16* Whhp  = (bf16*)(ws + off); off += (size_t)2*GATES*HID*2;       // 4 MiB
  float* bsum = (float*)(ws + off); off += (size_t)2*GATES*4;
  unsigned* flags = (unsigned*)(ws + off); off += (size_t)TT*8*64*4;   // 256 KiB
  unsigned* tflags = (unsigned*)(ws + off); off += 4096;               // 64 ctrs
  if (off > ws_size) return;  // workspace too small -> fail loudly (poison stays)

  hipMemsetAsync(flags, 0, (size_t)TT*8*64*4 + 4096, stream);
  k_prep<<<6144, 256, 0, stream>>>(words, chars, embW, cembW, convW, convb,
                                   WihF, WhhF, bihF, bhhF, WihB, WhhB, bihB, bhhB,
                                   featb, Wihp, Whhp, bsum);
  k_fused<<<256, 256, 0, stream>>>(Whhp, Wihp, featb, bsum, xW, hsbuf, flags, tflags);
  k_fc<<<TT, 256, 0, stream>>>(hsbuf, fcW, fcb, out);
}

// Round 14
// 649.820 us; speedup vs baseline: 1.0767x; 1.0767x over previous
//
#include <hip/hip_runtime.h>
#include <hip/hip_bf16.h>

#define TT 128
#define BATCH 64
#define WCH 16
#define CEMB 32
#define CCH 128
#define HID 512
#define GATES 2048
#define INF_ 428
#define KP 448
#define NOUT 20

typedef float f32x4 __attribute__((ext_vector_type(4)));
typedef __bf16 b8v __attribute__((ext_vector_type(8)));
typedef unsigned int u32x2 __attribute__((ext_vector_type(2)));
typedef unsigned int u32x4 __attribute__((ext_vector_type(4)));
typedef __hip_bfloat16 bf16;

__device__ __forceinline__ float sigm(float x){ return 1.f/(1.f+__expf(-x)); }
__device__ __forceinline__ float tanh_(float x){ float e=__expf(2.f*x); return (e-1.f)/(e+1.f); }
__device__ __forceinline__ unsigned pkbf(float lo, float hi){
  unsigned a = (unsigned)__builtin_bit_cast(unsigned short, __float2bfloat16(lo));
  unsigned b = (unsigned)__builtin_bit_cast(unsigned short, __float2bfloat16(hi));
  return a | (b << 16);
}

// ---------------- merged prep: flag clear + feat build (blocks 0..4095) +
// Wih pack (blocks 4096..6143). Whh pack eliminated (persist converts directly).
__global__ __launch_bounds__(256) void k_prep(
    const int* __restrict__ words, const int* __restrict__ chars,
    const float* __restrict__ embW, const float* __restrict__ cembW,
    const float* __restrict__ convW, const float* __restrict__ convb,
    const float* __restrict__ WihF, const float* __restrict__ bihF,
    const float* __restrict__ bhhF, const float* __restrict__ WihB,
    const float* __restrict__ bihB, const float* __restrict__ bhhB,
    bf16* __restrict__ featb, bf16* __restrict__ Wihp,
    float* __restrict__ bsum, unsigned* __restrict__ flags) {
  const int tid = threadIdx.x;
  {  // zero the step flags (replaces the memset dispatch)
    int idx = blockIdx.x*256 + tid;
    if (idx < TT*8*64) flags[idx] = 0u;
  }
  if (blockIdx.x < 4096) {
    int r = blockIdx.x*2 + (tid >> 7);
    int t2 = tid & 127;
    int t = r >> 6, b = r & 63;
    int wi = words[t*BATCH + b];
    const float* src = embW + (size_t)wi * 300;
    bf16* dst = featb + (size_t)r * KP;
    for (int k = t2; k < 300; k += 128) dst[k] = __float2bfloat16(src[k]);
    if (t2 < KP - INF_) dst[INF_ + t2] = __float2bfloat16(0.f);
    int cc = t2, g = cc >> 2;
    const int* ch = chars + ((size_t)b*TT + t)*WCH;
    float ce[WCH];
    #pragma unroll
    for (int w = 0; w < WCH; ++w) ce[w] = cembW[ch[w]*CEMB + g];
    float w0 = convW[cc*3], w1 = convW[cc*3+1], w2 = convW[cc*3+2];
    float m = -1e30f;
    #pragma unroll
    for (int p = 0; p < WCH-2; ++p) m = fmaxf(m, ce[p]*w0 + ce[p+1]*w1 + ce[p+2]*w2);
    dst[300 + cc] = __float2bfloat16(m + convb[cc]);
  } else {
    size_t tid0 = (size_t)(blockIdx.x - 4096)*256 + tid;
    size_t nthr = (size_t)2048*256;
    for (size_t idx = tid0; idx < (size_t)2*GATES*KP; idx += nthr) {
      int k = (int)(idx % KP);
      size_t rest = idx / KP;
      int p = (int)(rest & (GATES-1));
      int d = (int)(rest >> 11);
      int j = ((p>>5)<<3) | (p&7);
      int tau = (p>>3)&3;
      const float* Wih = d ? WihB : WihF;
      float v = (k < INF_) ? Wih[(size_t)(tau*HID + j)*INF_ + k] : 0.f;
      Wihp[idx] = __float2bfloat16(v);
    }
    for (size_t idx = tid0; idx < (size_t)2*GATES; idx += nthr) {
      int p = (int)(idx & (GATES-1));
      int d = (int)(idx >> 11);
      int j = ((p>>5)<<3) | (p&7);
      int tau = (p>>3)&3;
      int gg = tau*HID + j;
      bsum[idx] = d ? (bihB[gg]+bhhB[gg]) : (bihF[gg]+bhhF[gg]);
    }
  }
}

// ---------------- input-projection GEMM: M=4096 (permuted gates), N=8192, K=448
__global__ __launch_bounds__(256) void k_gemm(const bf16* __restrict__ Wihp,
      const bf16* __restrict__ featb, const float* __restrict__ bsum,
      bf16* __restrict__ xW) {
  __shared__ short As[128][72];
  __shared__ short Bs[128][72];
  int m0 = (blockIdx.x & 31) << 7;
  int n0 = (blockIdx.x >> 5) << 7;
  int tid = threadIdx.x;
  int lane = tid & 63;
  int wid = tid >> 6;
  int wr = wid >> 1, wc = wid & 1;
  int lm = lane & 15, kg = lane >> 4;
  f32x4 acc[4][4] = {};
  for (int k0 = 0; k0 < KP; k0 += 64) {
    #pragma unroll
    for (int c = 0; c < 4; ++c) {
      int ch = tid + c*256;
      int row = ch >> 3, k8 = (ch & 7) << 3;
      *(b8v*)&As[row][k8] = *(const b8v*)&Wihp[(size_t)(m0+row)*KP + k0 + k8];
      *(b8v*)&Bs[row][k8] = *(const b8v*)&featb[(size_t)(n0+row)*KP + k0 + k8];
    }
    __syncthreads();
    #pragma unroll
    for (int ks = 0; ks < 2; ++ks) {
      b8v a[4], bb[4];
      #pragma unroll
      for (int i = 0; i < 4; ++i) a[i]  = *(const b8v*)&As[wr*64 + i*16 + lm][ks*32 + kg*8];
      #pragma unroll
      for (int i = 0; i < 4; ++i) bb[i] = *(const b8v*)&Bs[wc*64 + i*16 + lm][ks*32 + kg*8];
      #pragma unroll
      for (int mi = 0; mi < 4; ++mi)
        #pragma unroll
        for (int ni = 0; ni < 4; ++ni)
          acc[mi][ni] = __builtin_amdgcn_mfma_f32_16x16x32_bf16(a[mi], bb[ni], acc[mi][ni], 0, 0, 0);
    }
    __syncthreads();
  }
  #pragma unroll
  for (int mi = 0; mi < 4; ++mi) {
    #pragma unroll
    for (int ni = 0; ni < 4; ++ni) {
      int r = n0 + wc*64 + ni*16 + lm;
      int t = r >> 6, b = r & 63;
      #pragma unroll
      for (int reg = 0; reg < 4; ++reg) {
        int G = m0 + wr*64 + mi*16 + kg*4 + reg;
        int d = G >> 11, p = G & (GATES-1);
        int jt_ = p >> 5, pp = p & 31;
        int noff = ((pp>>2)&3)*8 + (pp>>4)*4 + (pp&3);
        float v = acc[mi][ni][reg] + bsum[G];
        xW[(((size_t)t*2 + d)*64 + jt_)*2048 + b*32 + noff] = __float2bfloat16(v);
      }
    }
  }
}

// ---------------- persistent recurrence (r11 protocol; Whh converted f32->bf16
// in prologue). No FC tail this round (bisect).
__global__ __launch_bounds__(256, 1) void k_persist(
    const float* __restrict__ WhhF, const float* __restrict__ WhhB,
    const bf16* __restrict__ xW, bf16* __restrict__ hs,
    unsigned* __restrict__ flags) {
  __shared__ __align__(16) bf16 hlds[16*512];   // [b:16][slot:64][8], slot = j8 ^ (b&7)
  const int tid = threadIdx.x;
  const int widx = tid >> 6;
  const int wid = blockIdx.x*4 + widx;
  const int lane = tid & 63;
  const int dir = wid >> 8;
  const int btile = (wid >> 6) & 3;
  const int jt = wid & 63;
  const int grp = blockIdx.x >> 4;                       // dir*4 + btile
  const int wv = ((blockIdx.x & 15) << 2) | widx;        // wave slot in group
  const int b0 = btile << 4, pbase = jt << 5, jbase = jt << 3;
  const int col = lane & 15, kg = lane >> 4;

  // ---- Whh fragments: direct f32 load + convert (same RNE rounding as pack) ----
  u32x4 wq0[16], wq1[16];
  {
    const float* wsrc = dir ? WhhB : WhhF;
    int p0 = pbase + col, p1 = pbase + 16 + col;
    int j0 = ((p0>>5)<<3) | (p0&7), tau0 = (p0>>3)&3;
    int j1 = ((p1>>5)<<3) | (p1&7), tau1 = (p1>>3)&3;
    const float* r0 = wsrc + (size_t)(tau0*HID + j0)*HID;
    const float* r1 = wsrc + (size_t)(tau1*HID + j1)*HID;
    #pragma unroll
    for (int ks = 0; ks < 16; ++ks) {
      const float4* a0 = (const float4*)(r0 + ks*32 + kg*8);
      const float4* a1 = (const float4*)(r1 + ks*32 + kg*8);
      float4 f0 = a0[0], f1 = a0[1], g0 = a1[0], g1 = a1[1];
      wq0[ks][0] = pkbf(f0.x, f0.y); wq0[ks][1] = pkbf(f0.z, f0.w);
      wq0[ks][2] = pkbf(f1.x, f1.y); wq0[ks][3] = pkbf(f1.z, f1.w);
      wq1[ks][0] = pkbf(g0.x, g0.y); wq1[ks][1] = pkbf(g0.z, g0.w);
      wq1[ks][2] = pkbf(g1.x, g1.y); wq1[ks][3] = pkbf(g1.z, g1.w);
    }
    #pragma unroll
    for (int ks = 0; ks < 16; ++ks) {
      asm volatile("" : "+v"(wq0[ks]));
      asm volatile("" : "+v"(wq1[ks]));
    }
  }
  const bf16* const xwbase = xW + (size_t)jt*2048 + (b0 + col)*32 + kg*8;
  b8v nx;
  {
    const int t0 = dir ? TT-1 : 0;
    nx = *(const b8v*)(xwbase + (size_t)(t0*2 + dir)*64*2048);
  }
  f32x4 creg = {0.f, 0.f, 0.f, 0.f};

  for (int step = 0; step < TT; ++step) {
    const int tcur = dir ? (TT-1-step) : step;
    f32x4 acc0, acc1;
    if (step > 0) {
      // ---- wave 0 polls all 64 producer flags of this group (prev step) ----
      if (widx == 0) {
        const unsigned* fp = flags + (((size_t)(step-1)*8 + grp) << 6) + lane;
        for (;;) {
          unsigned v;
          asm volatile("global_load_dword %0, %1, off sc0 sc1\n\ts_waitcnt vmcnt(0)"
                       : "=v"(v) : "v"(fp) : "memory");
          if (__all(v == (unsigned)step)) break;
        }
      }
      __syncthreads();
      // ---- stage h(prev) for this btile: 16KB, once per block, swizzled ----
      const int tprev = dir ? tcur+1 : tcur-1;
      const bf16* hbase = hs + (((size_t)dir*TT + tprev)*BATCH + b0)*HID;
      u32x4 tmp0, tmp1, tmp2, tmp3;
      {
        const bf16* a0 = hbase + (size_t)tid*8;
        const bf16* a1 = a0 + 2048;
        const bf16* a2 = a0 + 4096;
        const bf16* a3 = a0 + 6144;
        asm volatile("global_load_dwordx4 %0, %1, off sc0 sc1" : "=v"(tmp0) : "v"(a0) : "memory");
        asm volatile("global_load_dwordx4 %0, %1, off sc0 sc1" : "=v"(tmp1) : "v"(a1) : "memory");
        asm volatile("global_load_dwordx4 %0, %1, off sc0 sc1" : "=v"(tmp2) : "v"(a2) : "memory");
        asm volatile("global_load_dwordx4 %0, %1, off sc0 sc1" : "=v"(tmp3) : "v"(a3) : "memory");
      }
      asm volatile("s_waitcnt vmcnt(0)" ::: "memory");   // h loads ready (covers nx too)
      __builtin_amdgcn_sched_barrier(0);
      #pragma unroll
      for (int p = 0; p < 4; ++p) {
        int c = p*256 + tid;
        int b = c >> 6, j8 = c & 63;
        int slot = j8 ^ (b & 7);
        u32x4 val = (p==0) ? tmp0 : (p==1) ? tmp1 : (p==2) ? tmp2 : tmp3;
        *(u32x4*)&hlds[b*512 + slot*8] = val;
      }
      __syncthreads();
      #pragma unroll
      for (int r = 0; r < 4; ++r) { acc0[r] = (float)nx[r]; acc1[r] = (float)nx[r+4]; }
      #pragma unroll
      for (int ks = 0; ks < 16; ++ks) {
        int slotr = (ks*4 + kg) ^ (col & 7);
        b8v bfrag = *(const b8v*)&hlds[col*512 + slotr*8];
        acc0 = __builtin_amdgcn_mfma_f32_16x16x32_bf16(__builtin_bit_cast(b8v, wq0[ks]), bfrag, acc0, 0, 0, 0);
        acc1 = __builtin_amdgcn_mfma_f32_16x16x32_bf16(__builtin_bit_cast(b8v, wq1[ks]), bfrag, acc1, 0, 0, 0);
      }
    } else {
      #pragma unroll
      for (int r = 0; r < 4; ++r) { acc0[r] = (float)nx[r]; acc1[r] = (float)nx[r+4]; }
    }
    f32x4 fsh, osh;
    #pragma unroll
    for (int r = 0; r < 4; ++r) {
      fsh[r] = __shfl_xor(acc0[r], 32);
      osh[r] = __shfl_xor(acc1[r], 32);
    }
    if (lane < 32) {
      unsigned us[4];
      #pragma unroll
      for (int r = 0; r < 4; ++r) {
        float zi = acc0[r], zf = fsh[r], zg = acc1[r], zo = osh[r];
        float co = (step > 0) ? creg[r] : 0.f;
        float cn = sigm(zf)*co + sigm(zi)*tanh_(zg);
        creg[r] = cn;
        us[r] = (unsigned)__builtin_bit_cast(unsigned short, __float2bfloat16(sigm(zo)*tanh_(cn)));
      }
      u32x2 pk; pk.x = us[0] | (us[1] << 16); pk.y = us[2] | (us[3] << 16);
      bf16* hpw = hs + (((size_t)dir*TT + tcur)*BATCH + b0 + col)*HID + jbase + kg*4;
      asm volatile("global_store_dwordx2 %0, %1, off sc0 sc1"
                   :: "v"(hpw), "v"(pk) : "memory");
    }
    if (step + 1 < TT) {
      // drain own h stores to LLC, then release this wave's flag (no RMW)
      asm volatile("s_waitcnt vmcnt(0)" ::: "memory");
      if (lane == 0) {
        unsigned* fw = flags + (((size_t)step*8 + grp) << 6) + wv;
        unsigned val = (unsigned)(step + 1);
        asm volatile("global_store_dword %0, %1, off sc0 sc1"
                     :: "v"(fw), "v"(val) : "memory");
      }
      // prefetch next step's xW (cached); flies across the next poll + h-stage
      const int tnext = dir ? tcur-1 : tcur+1;
      nx = *(const b8v*)(xwbase + (size_t)(tnext*2 + dir)*64*2048);
    }
  }
}

// ---------------- final FC (separate launch: kernel boundary = full coherence)
__global__ __launch_bounds__(256) void k_fc(const bf16* __restrict__ hs,
                     const float* __restrict__ fcW,
                     const float* __restrict__ fcb, float* __restrict__ out) {
  int t = blockIdx.x;
  for (int item = threadIdx.x; item < BATCH*NOUT; item += 256) {
    const int b = item / NOUT, o = item - b*NOUT;
    const b8v* hf8 = (const b8v*)(hs + ((size_t)t*BATCH + b)*HID);
    const b8v* hb8 = (const b8v*)(hs + (((size_t)TT + t)*BATCH + b)*HID);
    const float4* w4 = (const float4*)(fcW + (size_t)o*2*HID);
    float s = fcb[o];
    #pragma unroll 4
    for (int k = 0; k < 64; ++k) {
      b8v hv = hf8[k];
      float4 wa = w4[2*k], wb = w4[2*k+1];
      s += (float)hv[0]*wa.x + (float)hv[1]*wa.y + (float)hv[2]*wa.z + (float)hv[3]*wa.w
         + (float)hv[4]*wb.x + (float)hv[5]*wb.y + (float)hv[6]*wb.z + (float)hv[7]*wb.w;
    }
    #pragma unroll 4
    for (int k = 0; k < 64; ++k) {
      b8v hv = hb8[k];
      float4 wa = w4[128 + 2*k], wb = w4[129 + 2*k];
      s += (float)hv[0]*wa.x + (float)hv[1]*wa.y + (float)hv[2]*wa.z + (float)hv[3]*wa.w
         + (float)hv[4]*wb.x + (float)hv[5]*wb.y + (float)hv[6]*wb.z + (float)hv[7]*wb.w;
    }
    out[((size_t)t*BATCH + b)*NOUT + o] = s;
  }
}

extern "C" void kernel_launch(void* const* d_in, const int* in_sizes, int n_in,
                              void* d_out, int out_size, void* d_ws, size_t ws_size,
                              hipStream_t stream) {
  const int* words = (const int*)d_in[0];
  const int* chars = (const int*)d_in[1];
  const float* embW = (const float*)d_in[2];
  const float* cembW = (const float*)d_in[3];
  const float* convW = (const float*)d_in[4];
  const float* convb = (const float*)d_in[5];
  const float* WihF = (const float*)d_in[6];
  const float* WhhF = (const float*)d_in[7];
  const float* bihF = (const float*)d_in[8];
  const float* bhhF = (const float*)d_in[9];
  const float* WihB = (const float*)d_in[10];
  const float* WhhB = (const float*)d_in[11];
  const float* bihB = (const float*)d_in[12];
  const float* bhhB = (const float*)d_in[13];
  const float* fcW = (const float*)d_in[14];
  const float* fcb = (const float*)d_in[15];
  float* out = (float*)d_out;

  char* ws = (char*)d_ws;
  size_t off = 0;
  bf16* xW    = (bf16*)(ws + off); off += (size_t)TT*2*GATES*BATCH*2;  // 64 MiB
  bf16* hsbuf = (bf16*)(ws + off); off += (size_t)2*TT*BATCH*HID*2;    // 16 MiB
  bf16* featb = (bf16*)(ws + off); off += (size_t)TT*BATCH*KP*2;       // 7 MiB
  bf16* Wihp  = (bf16*)(ws + off); off += (size_t)2*GATES*KP*2;        // 3.5 MiB
  float* bsum = (float*)(ws + off); off += (size_t)2*GATES*4;
  unsigned* flags = (unsigned*)(ws + off); off += (size_t)TT*8*64*4;   // 256 KiB
  if (off > ws_size) return;  // workspace too small -> fail loudly (poison stays)

  k_prep<<<6144, 256, 0, stream>>>(words, chars, embW, cembW, convW, convb,
                                   WihF, bihF, bhhF, WihB, bihB, bhhB,
                                   featb, Wihp, bsum, flags);
  k_gemm<<<2048, 256, 0, stream>>>(Wihp, featb, bsum, xW);
  k_persist<<<128, 256, 0, stream>>>(WhhF, WhhB, xW, hsbuf, flags);
  k_fc<<<TT, 256, 0, stream>>>(hsbuf, fcW, fcb, out);
}

// Round 15
// 647.646 us; speedup vs baseline: 1.0803x; 1.0034x over previous
//
#include <hip/hip_runtime.h>
#include <hip/hip_bf16.h>

#define TT 128
#define BATCH 64
#define WCH 16
#define CEMB 32
#define CCH 128
#define HID 512
#define GATES 2048
#define INF_ 428
#define KP 448
#define NOUT 20

typedef float f32x4 __attribute__((ext_vector_type(4)));
typedef __bf16 b8v __attribute__((ext_vector_type(8)));
typedef unsigned int u32x2 __attribute__((ext_vector_type(2)));
typedef unsigned int u32x4 __attribute__((ext_vector_type(4)));
typedef __hip_bfloat16 bf16;

__device__ __forceinline__ float sigm(float x){ return 1.f/(1.f+__expf(-x)); }
__device__ __forceinline__ float tanh_(float x){ float e=__expf(2.f*x); return (e-1.f)/(e+1.f); }
__device__ __forceinline__ unsigned pkbf(float lo, float hi){
  unsigned a = (unsigned)__builtin_bit_cast(unsigned short, __float2bfloat16(lo));
  unsigned b = (unsigned)__builtin_bit_cast(unsigned short, __float2bfloat16(hi));
  return a | (b << 16);
}

// ---------------- merged prep: flag clear + feat build (blocks 0..4095) +
// Wih pack (blocks 4096..6143). Whh pack eliminated (persist converts directly).
__global__ __launch_bounds__(256) void k_prep(
    const int* __restrict__ words, const int* __restrict__ chars,
    const float* __restrict__ embW, const float* __restrict__ cembW,
    const float* __restrict__ convW, const float* __restrict__ convb,
    const float* __restrict__ WihF, const float* __restrict__ bihF,
    const float* __restrict__ bhhF, const float* __restrict__ WihB,
    const float* __restrict__ bihB, const float* __restrict__ bhhB,
    bf16* __restrict__ featb, bf16* __restrict__ Wihp,
    float* __restrict__ bsum, unsigned* __restrict__ flags) {
  const int tid = threadIdx.x;
  {  // zero the step flags (replaces the memset dispatch)
    int idx = blockIdx.x*256 + tid;
    if (idx < TT*8*64) flags[idx] = 0u;
  }
  if (blockIdx.x < 4096) {
    int r = blockIdx.x*2 + (tid >> 7);
    int t2 = tid & 127;
    int t = r >> 6, b = r & 63;
    int wi = words[t*BATCH + b];
    const float* src = embW + (size_t)wi * 300;
    bf16* dst = featb + (size_t)r * KP;
    for (int k = t2; k < 300; k += 128) dst[k] = __float2bfloat16(src[k]);
    if (t2 < KP - INF_) dst[INF_ + t2] = __float2bfloat16(0.f);
    int cc = t2, g = cc >> 2;
    const int* ch = chars + ((size_t)b*TT + t)*WCH;
    float ce[WCH];
    #pragma unroll
    for (int w = 0; w < WCH; ++w) ce[w] = cembW[ch[w]*CEMB + g];
    float w0 = convW[cc*3], w1 = convW[cc*3+1], w2 = convW[cc*3+2];
    float m = -1e30f;
    #pragma unroll
    for (int p = 0; p < WCH-2; ++p) m = fmaxf(m, ce[p]*w0 + ce[p+1]*w1 + ce[p+2]*w2);
    dst[300 + cc] = __float2bfloat16(m + convb[cc]);
  } else {
    size_t tid0 = (size_t)(blockIdx.x - 4096)*256 + tid;
    size_t nthr = (size_t)2048*256;
    for (size_t idx = tid0; idx < (size_t)2*GATES*KP; idx += nthr) {
      int k = (int)(idx % KP);
      size_t rest = idx / KP;
      int p = (int)(rest & (GATES-1));
      int d = (int)(rest >> 11);
      int j = ((p>>5)<<3) | (p&7);
      int tau = (p>>3)&3;
      const float* Wih = d ? WihB : WihF;
      float v = (k < INF_) ? Wih[(size_t)(tau*HID + j)*INF_ + k] : 0.f;
      Wihp[idx] = __float2bfloat16(v);
    }
    for (size_t idx = tid0; idx < (size_t)2*GATES; idx += nthr) {
      int p = (int)(idx & (GATES-1));
      int d = (int)(idx >> 11);
      int j = ((p>>5)<<3) | (p&7);
      int tau = (p>>3)&3;
      int gg = tau*HID + j;
      bsum[idx] = d ? (bihB[gg]+bhhB[gg]) : (bihF[gg]+bhhF[gg]);
    }
  }
}

// ---------------- input-projection GEMM: M=4096 (permuted gates), N=8192, K=448.
// NEW: linear [128][64] LDS + granule XOR-swizzle, staged via global_load_lds
// width-16 (no VGPR round-trip). Swizzle: LDS granule p holds global
// (row=p>>3, gcol=(p&7)^(row&7)); read applies the same XOR (involution).
__global__ __launch_bounds__(256) void k_gemm(const bf16* __restrict__ Wihp,
      const bf16* __restrict__ featb, const float* __restrict__ bsum,
      bf16* __restrict__ xW) {
  __shared__ __align__(16) bf16 As[128*64];
  __shared__ __align__(16) bf16 Bs[128*64];
  const int m0 = (blockIdx.x & 31) << 7;
  const int n0 = (blockIdx.x >> 5) << 7;
  const int tid = threadIdx.x;
  const int lane = tid & 63;
  const int wv4 = tid >> 6;
  const int wr = wv4 >> 1, wc = wv4 & 1;
  const int lm = lane & 15, kg = lane >> 4;
  f32x4 acc[4][4] = {};
  for (int k0 = 0; k0 < KP; k0 += 64) {
    #pragma unroll
    for (int c = 0; c < 4; ++c) {
      const int pb = ((c*4 + wv4) << 6);        // wave-uniform granule base
      const int p = pb + lane;                  // this lane's granule
      const int row = p >> 3;
      const int gcol = (p & 7) ^ (row & 7);     // pre-swizzled global column
      const bf16* sA = Wihp  + (size_t)(m0 + row)*KP + k0 + gcol*8;
      const bf16* sB = featb + (size_t)(n0 + row)*KP + k0 + gcol*8;
      __builtin_amdgcn_global_load_lds((const void*)sA, (void*)&As[pb*8], 16, 0, 0);
      __builtin_amdgcn_global_load_lds((const void*)sB, (void*)&Bs[pb*8], 16, 0, 0);
    }
    __syncthreads();   // compiler drains vmcnt before s_barrier
    #pragma unroll
    for (int ks = 0; ks < 2; ++ks) {
      const int gsw = ((ks*4 + kg) ^ (lm & 7)) << 3;   // swizzled granule offset
      b8v a[4], bb[4];
      #pragma unroll
      for (int i = 0; i < 4; ++i) {
        a[i]  = *(const b8v*)&As[(wr*64 + i*16 + lm)*64 + gsw];
        bb[i] = *(const b8v*)&Bs[(wc*64 + i*16 + lm)*64 + gsw];
      }
      #pragma unroll
      for (int mi = 0; mi < 4; ++mi)
        #pragma unroll
        for (int ni = 0; ni < 4; ++ni)
          acc[mi][ni] = __builtin_amdgcn_mfma_f32_16x16x32_bf16(a[mi], bb[ni], acc[mi][ni], 0, 0, 0);
    }
    __syncthreads();
  }
  #pragma unroll
  for (int mi = 0; mi < 4; ++mi) {
    #pragma unroll
    for (int ni = 0; ni < 4; ++ni) {
      int r = n0 + wc*64 + ni*16 + lm;
      int t = r >> 6, b = r & 63;
      #pragma unroll
      for (int reg = 0; reg < 4; ++reg) {
        int G = m0 + wr*64 + mi*16 + kg*4 + reg;
        int d = G >> 11, p = G & (GATES-1);
        int jt_ = p >> 5, pp = p & 31;
        int noff = ((pp>>2)&3)*8 + (pp>>4)*4 + (pp&3);
        float v = acc[mi][ni][reg] + bsum[G];
        xW[(((size_t)t*2 + d)*64 + jt_)*2048 + b*32 + noff] = __float2bfloat16(v);
      }
    }
  }
}

// ---------------- persistent recurrence (r11 protocol; Whh converted f32->bf16
// in prologue). Frozen from round 14.
__global__ __launch_bounds__(256, 1) void k_persist(
    const float* __restrict__ WhhF, const float* __restrict__ WhhB,
    const bf16* __restrict__ xW, bf16* __restrict__ hs,
    unsigned* __restrict__ flags) {
  __shared__ __align__(16) bf16 hlds[16*512];   // [b:16][slot:64][8], slot = j8 ^ (b&7)
  const int tid = threadIdx.x;
  const int widx = tid >> 6;
  const int wid = blockIdx.x*4 + widx;
  const int lane = tid & 63;
  const int dir = wid >> 8;
  const int btile = (wid >> 6) & 3;
  const int jt = wid & 63;
  const int grp = blockIdx.x >> 4;                       // dir*4 + btile
  const int wv = ((blockIdx.x & 15) << 2) | widx;        // wave slot in group
  const int b0 = btile << 4, pbase = jt << 5, jbase = jt << 3;
  const int col = lane & 15, kg = lane >> 4;

  // ---- Whh fragments: direct f32 load + convert (same RNE rounding as pack) ----
  u32x4 wq0[16], wq1[16];
  {
    const float* wsrc = dir ? WhhB : WhhF;
    int p0 = pbase + col, p1 = pbase + 16 + col;
    int j0 = ((p0>>5)<<3) | (p0&7), tau0 = (p0>>3)&3;
    int j1 = ((p1>>5)<<3) | (p1&7), tau1 = (p1>>3)&3;
    const float* r0 = wsrc + (size_t)(tau0*HID + j0)*HID;
    const float* r1 = wsrc + (size_t)(tau1*HID + j1)*HID;
    #pragma unroll
    for (int ks = 0; ks < 16; ++ks) {
      const float4* a0 = (const float4*)(r0 + ks*32 + kg*8);
      const float4* a1 = (const float4*)(r1 + ks*32 + kg*8);
      float4 f0 = a0[0], f1 = a0[1], g0 = a1[0], g1 = a1[1];
      wq0[ks][0] = pkbf(f0.x, f0.y); wq0[ks][1] = pkbf(f0.z, f0.w);
      wq0[ks][2] = pkbf(f1.x, f1.y); wq0[ks][3] = pkbf(f1.z, f1.w);
      wq1[ks][0] = pkbf(g0.x, g0.y); wq1[ks][1] = pkbf(g0.z, g0.w);
      wq1[ks][2] = pkbf(g1.x, g1.y); wq1[ks][3] = pkbf(g1.z, g1.w);
    }
    #pragma unroll
    for (int ks = 0; ks < 16; ++ks) {
      asm volatile("" : "+v"(wq0[ks]));
      asm volatile("" : "+v"(wq1[ks]));
    }
  }
  const bf16* const xwbase = xW + (size_t)jt*2048 + (b0 + col)*32 + kg*8;
  b8v nx;
  {
    const int t0 = dir ? TT-1 : 0;
    nx = *(const b8v*)(xwbase + (size_t)(t0*2 + dir)*64*2048);
  }
  f32x4 creg = {0.f, 0.f, 0.f, 0.f};

  for (int step = 0; step < TT; ++step) {
    const int tcur = dir ? (TT-1-step) : step;
    f32x4 acc0, acc1;
    if (step > 0) {
      // ---- wave 0 polls all 64 producer flags of this group (prev step) ----
      if (widx == 0) {
        const unsigned* fp = flags + (((size_t)(step-1)*8 + grp) << 6) + lane;
        for (;;) {
          unsigned v;
          asm volatile("global_load_dword %0, %1, off sc0 sc1\n\ts_waitcnt vmcnt(0)"
                       : "=v"(v) : "v"(fp) : "memory");
          if (__all(v == (unsigned)step)) break;
        }
      }
      __syncthreads();
      // ---- stage h(prev) for this btile: 16KB, once per block, swizzled ----
      const int tprev = dir ? tcur+1 : tcur-1;
      const bf16* hbase = hs + (((size_t)dir*TT + tprev)*BATCH + b0)*HID;
      u32x4 tmp0, tmp1, tmp2, tmp3;
      {
        const bf16* a0 = hbase + (size_t)tid*8;
        const bf16* a1 = a0 + 2048;
        const bf16* a2 = a0 + 4096;
        const bf16* a3 = a0 + 6144;
        asm volatile("global_load_dwordx4 %0, %1, off sc0 sc1" : "=v"(tmp0) : "v"(a0) : "memory");
        asm volatile("global_load_dwordx4 %0, %1, off sc0 sc1" : "=v"(tmp1) : "v"(a1) : "memory");
        asm volatile("global_load_dwordx4 %0, %1, off sc0 sc1" : "=v"(tmp2) : "v"(a2) : "memory");
        asm volatile("global_load_dwordx4 %0, %1, off sc0 sc1" : "=v"(tmp3) : "v"(a3) : "memory");
      }
      asm volatile("s_waitcnt vmcnt(0)" ::: "memory");   // h loads ready (covers nx too)
      __builtin_amdgcn_sched_barrier(0);
      #pragma unroll
      for (int p = 0; p < 4; ++p) {
        int c = p*256 + tid;
        int b = c >> 6, j8 = c & 63;
        int slot = j8 ^ (b & 7);
        u32x4 val = (p==0) ? tmp0 : (p==1) ? tmp1 : (p==2) ? tmp2 : tmp3;
        *(u32x4*)&hlds[b*512 + slot*8] = val;
      }
      __syncthreads();
      #pragma unroll
      for (int r = 0; r < 4; ++r) { acc0[r] = (float)nx[r]; acc1[r] = (float)nx[r+4]; }
      #pragma unroll
      for (int ks = 0; ks < 16; ++ks) {
        int slotr = (ks*4 + kg) ^ (col & 7);
        b8v bfrag = *(const b8v*)&hlds[col*512 + slotr*8];
        acc0 = __builtin_amdgcn_mfma_f32_16x16x32_bf16(__builtin_bit_cast(b8v, wq0[ks]), bfrag, acc0, 0, 0, 0);
        acc1 = __builtin_amdgcn_mfma_f32_16x16x32_bf16(__builtin_bit_cast(b8v, wq1[ks]), bfrag, acc1, 0, 0, 0);
      }
    } else {
      #pragma unroll
      for (int r = 0; r < 4; ++r) { acc0[r] = (float)nx[r]; acc1[r] = (float)nx[r+4]; }
    }
    f32x4 fsh, osh;
    #pragma unroll
    for (int r = 0; r < 4; ++r) {
      fsh[r] = __shfl_xor(acc0[r], 32);
      osh[r] = __shfl_xor(acc1[r], 32);
    }
    if (lane < 32) {
      unsigned us[4];
      #pragma unroll
      for (int r = 0; r < 4; ++r) {
        float zi = acc0[r], zf = fsh[r], zg = acc1[r], zo = osh[r];
        float co = (step > 0) ? creg[r] : 0.f;
        float cn = sigm(zf)*co + sigm(zi)*tanh_(zg);
        creg[r] = cn;
        us[r] = (unsigned)__builtin_bit_cast(unsigned short, __float2bfloat16(sigm(zo)*tanh_(cn)));
      }
      u32x2 pk; pk.x = us[0] | (us[1] << 16); pk.y = us[2] | (us[3] << 16);
      bf16* hpw = hs + (((size_t)dir*TT + tcur)*BATCH + b0 + col)*HID + jbase + kg*4;
      asm volatile("global_store_dwordx2 %0, %1, off sc0 sc1"
                   :: "v"(hpw), "v"(pk) : "memory");
    }
    if (step + 1 < TT) {
      // drain own h stores to LLC, then release this wave's flag (no RMW)
      asm volatile("s_waitcnt vmcnt(0)" ::: "memory");
      if (lane == 0) {
        unsigned* fw = flags + (((size_t)step*8 + grp) << 6) + wv;
        unsigned val = (unsigned)(step + 1);
        asm volatile("global_store_dword %0, %1, off sc0 sc1"
                     :: "v"(fw), "v"(val) : "memory");
      }
      // prefetch next step's xW (cached); flies across the next poll + h-stage
      const int tnext = dir ? tcur-1 : tcur+1;
      nx = *(const b8v*)(xwbase + (size_t)(tnext*2 + dir)*64*2048);
    }
  }
}

// ---------------- final FC (separate launch: kernel boundary = full coherence)
__global__ __launch_bounds__(256) void k_fc(const bf16* __restrict__ hs,
                     const float* __restrict__ fcW,
                     const float* __restrict__ fcb, float* __restrict__ out) {
  int t = blockIdx.x;
  for (int item = threadIdx.x; item < BATCH*NOUT; item += 256) {
    const int b = item / NOUT, o = item - b*NOUT;
    const b8v* hf8 = (const b8v*)(hs + ((size_t)t*BATCH + b)*HID);
    const b8v* hb8 = (const b8v*)(hs + (((size_t)TT + t)*BATCH + b)*HID);
    const float4* w4 = (const float4*)(fcW + (size_t)o*2*HID);
    float s = fcb[o];
    #pragma unroll 4
    for (int k = 0; k < 64; ++k) {
      b8v hv = hf8[k];
      float4 wa = w4[2*k], wb = w4[2*k+1];
      s += (float)hv[0]*wa.x + (float)hv[1]*wa.y + (float)hv[2]*wa.z + (float)hv[3]*wa.w
         + (float)hv[4]*wb.x + (float)hv[5]*wb.y + (float)hv[6]*wb.z + (float)hv[7]*wb.w;
    }
    #pragma unroll 4
    for (int k = 0; k < 64; ++k) {
      b8v hv = hb8[k];
      float4 wa = w4[128 + 2*k], wb = w4[129 + 2*k];
      s += (float)hv[0]*wa.x + (float)hv[1]*wa.y + (float)hv[2]*wa.z + (float)hv[3]*wa.w
         + (float)hv[4]*wb.x + (float)hv[5]*wb.y + (float)hv[6]*wb.z + (float)hv[7]*wb.w;
    }
    out[((size_t)t*BATCH + b)*NOUT + o] = s;
  }
}

extern "C" void kernel_launch(void* const* d_in, const int* in_sizes, int n_in,
                              void* d_out, int out_size, void* d_ws, size_t ws_size,
                              hipStream_t stream) {
  const int* words = (const int*)d_in[0];
  const int* chars = (const int*)d_in[1];
  const float* embW = (const float*)d_in[2];
  const float* cembW = (const float*)d_in[3];
  const float* convW = (const float*)d_in[4];
  const float* convb = (const float*)d_in[5];
  const float* WihF = (const float*)d_in[6];
  const float* WhhF = (const float*)d_in[7];
  const float* bihF = (const float*)d_in[8];
  const float* bhhF = (const float*)d_in[9];
  const float* WihB = (const float*)d_in[10];
  const float* WhhB = (const float*)d_in[11];
  const float* bihB = (const float*)d_in[12];
  const float* bhhB = (const float*)d_in[13];
  const float* fcW = (const float*)d_in[14];
  const float* fcb = (const float*)d_in[15];
  float* out = (float*)d_out;

  char* ws = (char*)d_ws;
  size_t off = 0;
  bf16* xW    = (bf16*)(ws + off); off += (size_t)TT*2*GATES*BATCH*2;  // 64 MiB
  bf16* hsbuf = (bf16*)(ws + off); off += (size_t)2*TT*BATCH*HID*2;    // 16 MiB
  bf16* featb = (bf16*)(ws + off); off += (size_t)TT*BATCH*KP*2;       // 7 MiB
  bf16* Wihp  = (bf16*)(ws + off); off += (size_t)2*GATES*KP*2;        // 3.5 MiB
  float* bsum = (float*)(ws + off); off += (size_t)2*GATES*4;
  unsigned* flags = (unsigned*)(ws + off); off += (size_t)TT*8*64*4;   // 256 KiB
  if (off > ws_size) return;  // workspace too small -> fail loudly (poison stays)

  k_prep<<<6144, 256, 0, stream>>>(words, chars, embW, cembW, convW, convb,
                                   WihF, bihF, bhhF, WihB, bihB, bhhB,
                                   featb, Wihp, bsum, flags);
  k_gemm<<<2048, 256, 0, stream>>>(Wihp, featb, bsum, xW);
  k_persist<<<128, 256, 0, stream>>>(WhhF, WhhB, xW, hsbuf, flags);
  k_fc<<<TT, 256, 0, stream>>>(hsbuf, fcW, fcb, out);
}